// Round 7
// baseline (345.599 us; speedup 1.0000x reference)
//
#include <hip/hip_runtime.h>
#include <math.h>

#define B_ 2
#define H_ 16
#define L_ 2048
#define D_ 64
#define NCH (L_ / 64)
#define NWG (B_ * H_ * (L_ / 64))   // 1024
#define OUT_ELEMS ((size_t)B_ * H_ * L_ * D_)
#define PITCH 72
// SCALE * log2(e): scores computed directly in exp2 domain
#define C1 0.180336880f

typedef _Float16 half8 __attribute__((ext_vector_type(8)));
typedef _Float16 half4_t __attribute__((ext_vector_type(4)));
typedef float f32x4 __attribute__((ext_vector_type(4)));
typedef int i32x4 __attribute__((ext_vector_type(4)));
typedef unsigned int u32;
typedef u32 u32x4 __attribute__((ext_vector_type(4)));
typedef u32 u32x2 __attribute__((ext_vector_type(2)));

// Block = 256 threads = 4 waves; block owns (b, h, 64 q-rows); wave owns 16.
// Swapped QK^T: acc[kb][r] = S[k = kc+kb*16+lg*4+r][q = q0+wv*16+lr] (log2 units).
// Flat softmax (no max): P = exp2(s)/l, l summed online. Double-buffered K/V,
// ONE barrier per chunk. P redistributed for PV via shuffles (no P LDS).
__global__ __launch_bounds__(256, 4) void attn_kernel(
    const float* __restrict__ Q, const float* __restrict__ K,
    const float* __restrict__ V, const int* __restrict__ M,
    float* __restrict__ out, float* __restrict__ score)
{
  // XCD-aware swizzle: XCD x gets contiguous logical ids; qt-fastest decode
  // => resident blocks on an XCD share few bh (K/V stay in that XCD's L2).
  const int bid = blockIdx.x;
  const int lid = (bid & 7) * (NWG / 8) + (bid >> 3);
  const int qt = lid & 31, h = (lid >> 5) & 15, b = lid >> 9;

  const int bh = b * H_ + h;
  const int q0 = qt * 64;
  const int tid = threadIdx.x;
  const int wv = tid >> 6, lane = tid & 63;
  const int lr = lane & 15, lg = lane >> 4;
  const int qrow = q0 + wv * 16 + lr;

  __shared__ _Float16 Klds[2][64][PITCH];   // K chunk [k][d], double-buffered
  __shared__ _Float16 Vlds[2][64][PITCH];   // V chunk [d][k], double-buffered

  const float* kbase = K + (size_t)bh * L_ * D_;
  const float* vbase = V + (size_t)bh * L_ * D_;
  const int* mrow = M + (size_t)b * L_ * L_ + (size_t)qrow * L_;
  float* srow = score + ((size_t)bh * L_ + qrow) * L_;
  float* ob = out + (size_t)(bh * L_ + q0) * D_;

  // ---- Q fragment (B-operand), pre-scaled by SCALE*log2e ----
  half8 qf[2];
  {
    const float* qr = Q + (size_t)(bh * L_ + qrow) * D_;
#pragma unroll
    for (int f = 0; f < 2; ++f) {
      f32x4 x = *(const f32x4*)(qr + f * 32 + lg * 8);
      f32x4 y = *(const f32x4*)(qr + f * 32 + lg * 8 + 4);
      qf[f] = half8{(_Float16)(x[0]*C1), (_Float16)(x[1]*C1), (_Float16)(x[2]*C1), (_Float16)(x[3]*C1),
                    (_Float16)(y[0]*C1), (_Float16)(y[1]*C1), (_Float16)(y[2]*C1), (_Float16)(y[3]*C1)};
    }
  }

  const int ksr = tid >> 2, ksd = (tid & 3) * 16;       // K staging: row, 16-d slice
  const int vk0 = (tid & 15) * 4, vd0 = (tid >> 4) * 4; // V staging: 4k x 4d block

  auto loadK4 = [&](int kc, f32x4* r) {
    const float* s = kbase + (size_t)(kc + ksr) * D_ + ksd;
    r[0] = ((const f32x4*)s)[0]; r[1] = ((const f32x4*)s)[1];
    r[2] = ((const f32x4*)s)[2]; r[3] = ((const f32x4*)s)[3];
  };
  auto writeK = [&](_Float16 (*dst)[PITCH], const f32x4* r) {
    half8 lo = half8{(_Float16)r[0][0], (_Float16)r[0][1], (_Float16)r[0][2], (_Float16)r[0][3],
                     (_Float16)r[1][0], (_Float16)r[1][1], (_Float16)r[1][2], (_Float16)r[1][3]};
    half8 hi = half8{(_Float16)r[2][0], (_Float16)r[2][1], (_Float16)r[2][2], (_Float16)r[2][3],
                     (_Float16)r[3][0], (_Float16)r[3][1], (_Float16)r[3][2], (_Float16)r[3][3]};
    *(half8*)&dst[ksr][ksd] = lo;
    *(half8*)&dst[ksr][ksd + 8] = hi;
  };
  auto loadV4 = [&](int kc, f32x4* r) {
#pragma unroll
    for (int i = 0; i < 4; ++i)
      r[i] = *(const f32x4*)(vbase + (size_t)(kc + vk0 + i) * D_ + vd0);
  };
  auto writeV = [&](_Float16 (*dst)[PITCH], const f32x4* r) {
#pragma unroll
    for (int j = 0; j < 4; ++j) {
      *(half4_t*)&dst[vd0 + j][vk0] =
          half4_t{(_Float16)r[0][j], (_Float16)r[1][j],
                  (_Float16)r[2][j], (_Float16)r[3][j]};
    }
  };

  // ======================= pass A: per-lane row sum =======================
  float l_l = 0.f;
  {
    f32x4 kr[4];
    loadK4(0, kr);
    writeK(Klds[0], kr);
  }
  __syncthreads();

  for (int c = 0; c < NCH; ++c) {
    const int kc = c * 64, cur = c & 1;
    f32x4 kr[4];
    if (c < NCH - 1) loadK4(kc + 64, kr);
    i32x4 mq[4];
#pragma unroll
    for (int kb = 0; kb < 4; ++kb)
      mq[kb] = *(const i32x4*)(mrow + kc + kb * 16 + lg * 4);

    f32x4 acc[4] = {f32x4{0,0,0,0}, f32x4{0,0,0,0}, f32x4{0,0,0,0}, f32x4{0,0,0,0}};
    __builtin_amdgcn_s_setprio(1);
#pragma unroll
    for (int kb = 0; kb < 4; ++kb) {
      half8 a0 = *(const half8*)&Klds[cur][kb * 16 + lr][lg * 8];
      half8 a1 = *(const half8*)&Klds[cur][kb * 16 + lr][32 + lg * 8];
      acc[kb] = __builtin_amdgcn_mfma_f32_16x16x32_f16(a0, qf[0], acc[kb], 0, 0, 0);
      acc[kb] = __builtin_amdgcn_mfma_f32_16x16x32_f16(a1, qf[1], acc[kb], 0, 0, 0);
    }
    __builtin_amdgcn_s_setprio(0);

    float cs = 0.f;
#pragma unroll
    for (int kb = 0; kb < 4; ++kb)
#pragma unroll
      for (int r = 0; r < 4; ++r)
        cs += exp2f(mq[kb][r] != 0 ? acc[kb][r] : -INFINITY);
    l_l += cs;

    if (c < NCH - 1) writeK(Klds[cur ^ 1], kr);
    __syncthreads();
  }

  // cross-lg merge (lanes differing in bits 4,5 share a q-row)
  float lc = l_l;
  lc += __shfl_xor(lc, 16);
  lc += __shfl_xor(lc, 32);
  const float inv_l = (lc > 0.f) ? 1.f / lc : 0.f;

  // ============ pass B: write P (score), accumulate O = P*V ============
  {
    f32x4 kr[4], vr[4];
    loadK4(0, kr);
    loadV4(0, vr);
    writeK(Klds[0], kr);
    writeV(Vlds[0], vr);
  }
  __syncthreads();

  f32x4 o_acc[4] = {f32x4{0,0,0,0}, f32x4{0,0,0,0}, f32x4{0,0,0,0}, f32x4{0,0,0,0}};

  const int s0lane = lr + 32 * (lg & 1);   // P-shuffle sources
  const int s1lane = s0lane + 16;
  const bool hisel = (lg & 2) != 0;

  for (int c = 0; c < NCH; ++c) {
    const int kc = c * 64, cur = c & 1;
    f32x4 krP[4], vrP[4];
    if (c < NCH - 1) {
      loadK4(kc + 64, krP);
      loadV4(kc + 64, vrP);
    }
    i32x4 mq[4];
#pragma unroll
    for (int kb = 0; kb < 4; ++kb)
      mq[kb] = *(const i32x4*)(mrow + kc + kb * 16 + lg * 4);

    f32x4 acc[4] = {f32x4{0,0,0,0}, f32x4{0,0,0,0}, f32x4{0,0,0,0}, f32x4{0,0,0,0}};
    __builtin_amdgcn_s_setprio(1);
#pragma unroll
    for (int kb = 0; kb < 4; ++kb) {
      half8 a0 = *(const half8*)&Klds[cur][kb * 16 + lr][lg * 8];
      half8 a1 = *(const half8*)&Klds[cur][kb * 16 + lr][32 + lg * 8];
      acc[kb] = __builtin_amdgcn_mfma_f32_16x16x32_f16(a0, qf[0], acc[kb], 0, 0, 0);
      acc[kb] = __builtin_amdgcn_mfma_f32_16x16x32_f16(a1, qf[1], acc[kb], 0, 0, 0);
    }
    __builtin_amdgcn_s_setprio(0);

    // P = exp2(s)/l ; plain store to score; pack halves for shuffle
    u32 phu[8];
#pragma unroll
    for (int kb = 0; kb < 4; ++kb) {
      f32x4 p4;
#pragma unroll
      for (int r = 0; r < 4; ++r)
        p4[r] = exp2f(mq[kb][r] != 0 ? acc[kb][r] : -INFINITY) * inv_l;
      *(f32x4*)(srow + kc + kb * 16 + lg * 4) = p4;
      half4_t hp = half4_t{(_Float16)p4[0], (_Float16)p4[1],
                           (_Float16)p4[2], (_Float16)p4[3]};
      u32x2 uu = __builtin_bit_cast(u32x2, hp);
      phu[2 * kb] = uu[0];
      phu[2 * kb + 1] = uu[1];
    }

    // Redistribute P: lane(lr,lg) gathers P[q=lr][k=ks*32+lg*8+j] from
    // lanes s0lane (j=0..3) and s1lane (j=4..7), kb-half chosen by lg&2.
    __builtin_amdgcn_s_setprio(1);
#pragma unroll
    for (int ks = 0; ks < 2; ++ks) {
      int a0 = __shfl((int)phu[4 * ks + 0], s0lane);
      int a1 = __shfl((int)phu[4 * ks + 1], s0lane);
      int a2 = __shfl((int)phu[4 * ks + 2], s0lane);
      int a3 = __shfl((int)phu[4 * ks + 3], s0lane);
      int b0 = __shfl((int)phu[4 * ks + 0], s1lane);
      int b1 = __shfl((int)phu[4 * ks + 1], s1lane);
      int b2 = __shfl((int)phu[4 * ks + 2], s1lane);
      int b3 = __shfl((int)phu[4 * ks + 3], s1lane);
      u32x4 pau = u32x4{(u32)(hisel ? a2 : a0), (u32)(hisel ? a3 : a1),
                        (u32)(hisel ? b2 : b0), (u32)(hisel ? b3 : b1)};
      half8 pa = __builtin_bit_cast(half8, pau);
#pragma unroll
      for (int db = 0; db < 4; ++db) {
        half8 vf = *(const half8*)&Vlds[cur][db * 16 + lr][ks * 32 + lg * 8];
        o_acc[db] = __builtin_amdgcn_mfma_f32_16x16x32_f16(pa, vf, o_acc[db], 0, 0, 0);
      }
    }
    __builtin_amdgcn_s_setprio(0);

    // stage next chunk, then ONE barrier
    if (c < NCH - 1) {
      writeK(Klds[cur ^ 1], krP);
      writeV(Vlds[cur ^ 1], vrP);
    }
    __syncthreads();
  }

  // ---- write O (NT): row = q (wv*16+lg*4+r), col = d (db*16+lr) ----
#pragma unroll
  for (int db = 0; db < 4; ++db)
#pragma unroll
    for (int r = 0; r < 4; ++r)
      __builtin_nontemporal_store(
          o_acc[db][r], ob + (size_t)(wv * 16 + lg * 4 + r) * D_ + db * 16 + lr);
}

extern "C" void kernel_launch(void* const* d_in, const int* in_sizes, int n_in,
                              void* d_out, int out_size, void* d_ws, size_t ws_size,
                              hipStream_t stream) {
  const float* q = (const float*)d_in[0];
  const float* k = (const float*)d_in[1];
  const float* v = (const float*)d_in[2];
  const int* mask = (const int*)d_in[3];
  float* out = (float*)d_out;
  float* score = out + OUT_ELEMS;

  attn_kernel<<<dim3(NWG), 256, 0, stream>>>(q, k, v, mask, out, score);
}